// Round 1
// baseline (315.402 us; speedup 1.0000x reference)
//
#include <hip/hip_runtime.h>
#include <hip/hip_bf16.h>
#include <stdint.h>

#define IN_F 4096
#define OUT_F 11008
#define TOKENS 32
#define NELEM_W (OUT_F * IN_F)        // 45088768 weights, ~180 MB fp32
#define OUT_ELEMS (TOKENS * OUT_F)    // 352256

typedef __attribute__((ext_vector_type(8))) __bf16 bf16x8;
typedef __attribute__((ext_vector_type(4))) float  f32x4;

// d_ws layout (bytes):
//   [0, 64):          scalars: f[0]=sample_absum (atomic), u[1]=exc_count,
//                              f[2]=thr (exact), f[3]=scale (exact)
//   [64, +256K):      xb — x converted to bf16
//   [262208, +1.38M): gpart — UNSCALED fp32 output (fixup atomics land here)
//   [1671232, +2752): apart — 688 per-block sum(|w|) partials
//   [1675264, +2M):   exception buffer, uint2 {w bits, o*4096+i}
#define XB_OFF    64
#define GPART_OFF 262208
#define APART_OFF 1671232
#define EXC_OFF   1675264
#define EXC_CAP   262144u
#define EXC_LOC   1024

#define N_SAMPLE_F 1048576.0f   // 256 blocks * 256 thr * 4 float4 * 4
#define DELTA 0.004f            // window half-width ~4.3 sigma of thr_hat error

// fp32 -> bf16 bits (round-to-nearest-even), result in low 16
__device__ __forceinline__ uint32_t bfr(float v) {
    uint32_t u = __float_as_uint(v);
    uint32_t r = u + 0x7FFFu + ((u >> 16) & 1u);
    return r >> 16;
}

// provisional threshold from the sampled |w| sum — MUST be bit-identical
// wherever recomputed (gemm + fixup), so both read the same wsf[0].
__device__ __forceinline__ float thr_hat_from(float ssum) {
    float m = ssum * (1.0f / N_SAMPLE_F);
    if (m < 1e-5f) m = 1e-5f;
    return 0.7f * m;
}

// ---------------- pass 0: sampled threshold + x->bf16 conversion ----------------
// Blocks 0..255: 1024 waves, wave wid samples 4x64 coalesced float4 from its
// 11008-float4 stripe (1024*11008 = 11272192 = whole w). n = 1,048,576 floats.
// Blocks 256..319: x conversion (16384 threads, 8 floats each).
__global__ __launch_bounds__(256) void sample_xcvt_kernel(const float* __restrict__ w,
                                                          const float* __restrict__ x,
                                                          float* __restrict__ wsf,
                                                          uint4* __restrict__ xb) {
    if (blockIdx.x >= 256) {
        int i = (blockIdx.x - 256) * 256 + threadIdx.x;
        const float4* x4 = (const float4*)x;
        float4 a0 = x4[i * 2];
        float4 a1 = x4[i * 2 + 1];
        uint4 o;
        o.x = bfr(a0.x) | (bfr(a0.y) << 16);
        o.y = bfr(a0.z) | (bfr(a0.w) << 16);
        o.z = bfr(a1.x) | (bfr(a1.y) << 16);
        o.w = bfr(a1.z) | (bfr(a1.w) << 16);
        xb[i] = o;
        return;
    }
    const int wv   = threadIdx.x >> 6;
    const int lane = threadIdx.x & 63;
    const int wid  = blockIdx.x * 4 + wv;
    const float4* w4 = (const float4*)w;
    size_t base = (size_t)wid * 11008 + lane;
    float s = 0.f;
#pragma unroll
    for (int r = 0; r < 4; ++r) {
        float4 v = w4[base + (size_t)r * 2752];
        s += __builtin_fabsf(v.x) + __builtin_fabsf(v.y) +
             __builtin_fabsf(v.z) + __builtin_fabsf(v.w);
    }
    for (int off = 32; off > 0; off >>= 1) s += __shfl_down(s, off, 64);
    __shared__ float ws4[4];
    if (lane == 0) ws4[wv] = s;
    __syncthreads();
    if (threadIdx.x == 0) atomicAdd(&wsf[0], ws4[0] + ws4[1] + ws4[2] + ws4[3]);
}

// ---------------- ternarize helpers ----------------
__device__ __forceinline__ uint32_t tern1(float v, float thr) {
    uint32_t u  = __float_as_uint(v);
    uint32_t pm = (u & 0x80000000u) | 0x3F800000u;   // +-1.0f
    return (__builtin_fabsf(v) > thr) ? pm : 0u;
}

__device__ __forceinline__ uint2 tern4(float4 b, float thr) {
    uint32_t q0 = tern1(b.x, thr), q1 = tern1(b.y, thr);
    uint32_t q2 = tern1(b.z, thr), q3 = tern1(b.w, thr);
    uint2 r;
    r.x = __builtin_amdgcn_perm(q1, q0, 0x07060302u);
    r.y = __builtin_amdgcn_perm(q3, q2, 0x07060302u);
    return r;
}

// ---------------- pass 1: single-read ternary GEMM + exact absum + exceptions --
// Grid: 688 blocks x 256 thr (4 waves). Block og owns 16 output rows, full K.
// Wave wv covers k = wv*1024..+1024 in 16 chunks of 64. Same staging / MFMA
// core as the verified 2-wave version; kh merged into the block, split-K gone.
#define CHUNKS 16
#define WAVE_LDS 2304          // 16 rows * 144 B
#define STAGE_BYTES 9216       // 4 waves; reduce buf (4*512*4 B) reuses this

__global__ __launch_bounds__(256, 3) void ternary_gemm(const float* __restrict__ w,
                                                       const float* __restrict__ wsf,
                                                       const __bf16* __restrict__ xb,
                                                       float* __restrict__ gpart,
                                                       float* __restrict__ apart,
                                                       uint2* __restrict__ excg,
                                                       unsigned int* __restrict__ exc_cnt) {
    __shared__ char smem_raw[STAGE_BYTES];
    __shared__ uint2 exc_lds[EXC_LOC];
    __shared__ unsigned int exc_n;
    __shared__ unsigned int exc_base_s;
    __shared__ float wsum4[4];

    const float th = thr_hat_from(wsf[0]);   // provisional threshold
    const float lo = th * (1.0f - DELTA);
    const float hi = th * (1.0f + DELTA);

    const int og   = blockIdx.x;
    const int tid  = threadIdx.x;
    const int wv   = tid >> 6;
    const int lane = tid & 63;
    const int col  = lane & 15;     // fragment: output col in group / token
    const int quad = lane >> 4;     // fragment k sub-block; staging row group
    const int rlan = lane & 15;     // staging: 16-B slot within a row

    if (tid == 0) exc_n = 0u;
    __syncthreads();

    const int kw    = wv * 1024;
    const int obase = og * 16 + quad;          // row for r=0; +4r for r=1..3

    const float* wp = w + (size_t)obase * IN_F + kw + rlan * 4;
    char* stage = smem_raw + wv * WAVE_LDS;
    char* wr    = stage + quad * 144 + rlan * 8;
    const char* rd = stage + col * 144;
    const __bf16* xq = xb + (size_t)col * IN_F + kw + quad * 8;

    f32x4 acc0 = {0.f, 0.f, 0.f, 0.f};
    f32x4 acc1 = {0.f, 0.f, 0.f, 0.f};
    float sab = 0.f;

    float4 wb[2][4];
    bf16x8 xv[2][4];

#pragma unroll
    for (int c = 0; c < 2; ++c) {
        const float*  np = wp + c * 64;
        const __bf16* xn = xq + c * 64;
        wb[c][0] = *(const float4*)(np);
        wb[c][1] = *(const float4*)(np + 4 * IN_F);
        wb[c][2] = *(const float4*)(np + 8 * IN_F);
        wb[c][3] = *(const float4*)(np + 12 * IN_F);
        xv[c][0] = *(const bf16x8*)(xn);
        xv[c][1] = *(const bf16x8*)(xn + 32);
        xv[c][2] = *(const bf16x8*)(xn + 16 * IN_F);
        xv[c][3] = *(const bf16x8*)(xn + 16 * IN_F + 32);
    }

// rare-path exception record (expected ~2 hits per thread over whole kernel)
#define WCHECK(f, oo, ii)                                                      \
    {                                                                          \
        float a_ = __builtin_fabsf(f);                                         \
        if (a_ > lo && a_ < hi) {                                              \
            unsigned int p_ = atomicAdd(&exc_n, 1u);                           \
            if (p_ < (unsigned int)EXC_LOC) {                                  \
                uint2 e_;                                                      \
                e_.x = __float_as_uint(f);                                     \
                e_.y = (unsigned int)((oo) * 4096 + (ii));                     \
                exc_lds[p_] = e_;                                              \
            }                                                                  \
        }                                                                      \
    }

#define PROC4(vv, rr, cc)                                                      \
    {                                                                          \
        sab += __builtin_fabsf(vv.x) + __builtin_fabsf(vv.y) +                 \
               __builtin_fabsf(vv.z) + __builtin_fabsf(vv.w);                  \
        int o_  = obase + 4 * (rr);                                            \
        int ib_ = kw + (cc) * 64 + rlan * 4;                                   \
        WCHECK(vv.x, o_, ib_ + 0)                                              \
        WCHECK(vv.y, o_, ib_ + 1)                                              \
        WCHECK(vv.z, o_, ib_ + 2)                                              \
        WCHECK(vv.w, o_, ib_ + 3)                                              \
    }

#define GEMM_BODY(c, cur)                                                      \
    {                                                                          \
        uint2 t0 = tern4(wb[cur][0], th);                                      \
        uint2 t1 = tern4(wb[cur][1], th);                                      \
        uint2 t2 = tern4(wb[cur][2], th);                                      \
        uint2 t3 = tern4(wb[cur][3], th);                                      \
        PROC4(wb[cur][0], 0, c)                                                \
        PROC4(wb[cur][1], 1, c)                                                \
        PROC4(wb[cur][2], 2, c)                                                \
        PROC4(wb[cur][3], 3, c)                                                \
        *(uint2*)(wr)        = t0;                                             \
        *(uint2*)(wr + 576)  = t1;                                             \
        *(uint2*)(wr + 1152) = t2;                                             \
        *(uint2*)(wr + 1728) = t3;                                             \
        bf16x8 a00 = xv[cur][0], a01 = xv[cur][1];                             \
        bf16x8 a10 = xv[cur][2], a11 = xv[cur][3];                             \
        if ((c) + 2 < CHUNKS) {                                                \
            const float*  np = wp + ((c) + 2) * 64;                            \
            const __bf16* xn = xq + ((c) + 2) * 64;                            \
            wb[cur][0] = *(const float4*)(np);                                 \
            wb[cur][1] = *(const float4*)(np + 4 * IN_F);                      \
            wb[cur][2] = *(const float4*)(np + 8 * IN_F);                      \
            wb[cur][3] = *(const float4*)(np + 12 * IN_F);                     \
            xv[cur][0] = *(const bf16x8*)(xn);                                 \
            xv[cur][1] = *(const bf16x8*)(xn + 32);                            \
            xv[cur][2] = *(const bf16x8*)(xn + 16 * IN_F);                     \
            xv[cur][3] = *(const bf16x8*)(xn + 16 * IN_F + 32);                \
        }                                                                      \
        bf16x8 bw0 = *(const bf16x8*)(rd + quad * 16);                         \
        bf16x8 bw1 = *(const bf16x8*)(rd + 64 + quad * 16);                    \
        acc0 = __builtin_amdgcn_mfma_f32_16x16x32_bf16(a00, bw0, acc0, 0, 0, 0); \
        acc1 = __builtin_amdgcn_mfma_f32_16x16x32_bf16(a10, bw0, acc1, 0, 0, 0); \
        acc0 = __builtin_amdgcn_mfma_f32_16x16x32_bf16(a01, bw1, acc0, 0, 0, 0); \
        acc1 = __builtin_amdgcn_mfma_f32_16x16x32_bf16(a11, bw1, acc1, 0, 0, 0); \
    }

    for (int c = 0; c < CHUNKS; c += 2) {
        GEMM_BODY(c, 0)
        GEMM_BODY(c + 1, 1)
    }
#undef GEMM_BODY
#undef PROC4
#undef WCHECK

    __syncthreads();
    unsigned int nloc = exc_n;
    if (nloc > (unsigned int)EXC_LOC) nloc = (unsigned int)EXC_LOC;

    // exact |w| partial: wave reduce, cross-wave via LDS
    for (int off = 32; off > 0; off >>= 1) sab += __shfl_down(sab, off, 64);
    if (lane == 0) wsum4[wv] = sab;
    if (tid == 0) exc_base_s = atomicAdd(exc_cnt, nloc);
    __syncthreads();
    if (tid == 0) apart[og] = wsum4[0] + wsum4[1] + wsum4[2] + wsum4[3];

    // flush exceptions (coalesced, typically <=2 iterations)
    unsigned int gb = exc_base_s;
    for (unsigned int e = tid; e < nloc; e += 256) {
        unsigned int g = gb + e;
        if (g < EXC_CAP) excg[g] = exc_lds[e];
    }

    // accumulate reduce across 4 waves (reuses staging LDS; all past barrier)
    float* red   = (float*)smem_raw;
    float* basef = red + wv * 512;
#pragma unroll
    for (int r = 0; r < 4; ++r) basef[r * 64 + lane]       = acc0[r];
#pragma unroll
    for (int r = 0; r < 4; ++r) basef[256 + r * 64 + lane] = acc1[r];
    __syncthreads();

    for (int p = tid; p < 512; p += 256) {
        int t = p >> 4, cc2 = p & 15;
        int a = t >> 4;
        int q = (t >> 2) & 3;
        int r = t & 3;
        int idx = a * 256 + r * 64 + q * 16 + cc2;
        gpart[(size_t)t * OUT_F + og * 16 + cc2] =
            red[idx] + red[512 + idx] + red[1024 + idx] + red[1536 + idx];
    }
}

// ---------------- pass 2: exact mean -> thr/scale ----------------
__global__ __launch_bounds__(256) void finalize_kernel(const float* __restrict__ apart,
                                                       float* __restrict__ wsf) {
    float s = 0.f;
#pragma unroll
    for (int j = 0; j < 3; ++j) {
        int k = threadIdx.x + 256 * j;
        if (k < 688) s += apart[k];
    }
    for (int off = 32; off > 0; off >>= 1) s += __shfl_down(s, off, 64);
    __shared__ float wsum[4];
    int lane = threadIdx.x & 63;
    int wv   = threadIdx.x >> 6;
    if (lane == 0) wsum[wv] = s;
    __syncthreads();
    if (threadIdx.x == 0) {
        double mean = (double)(wsum[0] + wsum[1] + wsum[2] + wsum[3]) / (double)NELEM_W;
        if (mean < 1e-5) mean = 1e-5;
        float mf = (float)mean;
        wsf[2] = 0.7f * mf;   // exact threshold
        wsf[3] = mf;          // exact scale
    }
}

// ---------------- pass 3: exception fixup (patch unscaled gpart) ----------------
__global__ __launch_bounds__(256) void fixup_kernel(const uint2* __restrict__ excg,
                                                    const float* __restrict__ wsf,
                                                    const unsigned int* __restrict__ exc_cnt,
                                                    const __bf16* __restrict__ xb,
                                                    float* __restrict__ gpart) {
    const float thr = wsf[2];
    const float th  = thr_hat_from(wsf[0]);   // bit-identical to gemm's value
    unsigned int n = *exc_cnt;
    if (n > EXC_CAP) n = EXC_CAP;
    for (unsigned int g = blockIdx.x * 256 + threadIdx.x; g < n; g += gridDim.x * 256) {
        uint2 e = excg[g];
        float v = __uint_as_float(e.x);
        float a = __builtin_fabsf(v);
        bool qt = a > thr;   // true decision
        bool qh = a > th;    // decision the gemm used
        if (qt != qh) {
            float sgn = (e.x & 0x80000000u) ? -1.0f : 1.0f;
            float d   = qt ? sgn : -sgn;
            unsigned int o = e.y >> 12;
            unsigned int i = e.y & 4095u;
            const __bf16* xp = xb + i;
            for (int t = 0; t < TOKENS; ++t)
                atomicAdd(&gpart[(size_t)t * OUT_F + o], d * (float)xp[(size_t)t * IN_F]);
        }
    }
}

// ---------------- pass 4: scale to output ----------------
__global__ __launch_bounds__(256) void scale_kernel(const float* __restrict__ gpart,
                                                    const float* __restrict__ wsf,
                                                    float* __restrict__ out) {
    const float sc = wsf[3];
    int i = blockIdx.x * 256 + threadIdx.x;   // float4 index, 88064 total
    float4 a = ((const float4*)gpart)[i];
    float4 o;
    o.x = a.x * sc;
    o.y = a.y * sc;
    o.z = a.z * sc;
    o.w = a.w * sc;
    ((float4*)out)[i] = o;
}

extern "C" void kernel_launch(void* const* d_in, const int* in_sizes, int n_in,
                              void* d_out, int out_size, void* d_ws, size_t ws_size,
                              hipStream_t stream) {
    const float* x = (const float*)d_in[0];   // [32, 4096]
    const float* w = (const float*)d_in[1];   // [11008, 4096]
    float* out     = (float*)d_out;           // [32, 11008]
    char* ws       = (char*)d_ws;

    float*        wsf   = (float*)ws;
    unsigned int* wsu   = (unsigned int*)ws;
    uint4*        xb    = (uint4*)(ws + XB_OFF);
    float*        gpart = (float*)(ws + GPART_OFF);
    float*        apart = (float*)(ws + APART_OFF);
    uint2*        excg  = (uint2*)(ws + EXC_OFF);

    hipMemsetAsync(ws, 0, 64, stream);   // zero sample-sum + exception counter
    sample_xcvt_kernel<<<320, 256, 0, stream>>>(w, x, wsf, xb);
    ternary_gemm<<<OUT_F / 16, 256, 0, stream>>>(w, wsf, (const __bf16*)(ws + XB_OFF),
                                                 gpart, apart, excg, wsu + 1);
    finalize_kernel<<<1, 256, 0, stream>>>(apart, wsf);
    fixup_kernel<<<256, 256, 0, stream>>>(excg, wsf, wsu + 1,
                                          (const __bf16*)(ws + XB_OFF), gpart);
    scale_kernel<<<OUT_ELEMS / 4 / 256, 256, 0, stream>>>(gpart, wsf, out);
}